// Round 8
// baseline (446.965 us; speedup 1.0000x reference)
//
#include <hip/hip_runtime.h>
#include <stdint.h>

typedef unsigned long long u64;
typedef unsigned short u16;
typedef __attribute__((ext_vector_type(8))) short short8;
typedef __attribute__((ext_vector_type(4))) float f32x4;

// Problem constants
#define NB   16
#define NT   12
#define BTc  192     // NB*NT
#define NN   4096
#define DD   64
#define MM   128
#define TOPK 32
#define KTH  44      // threshold = 44th-largest of 128 group32-maxima (E[c]~54)
#define CAP  128     // candidate capacity (P(c>128) astronomically small)

// d_out float offsets (outputs concatenated flat)
#define SEL1_OFF 0ULL
#define SEL2_OFF 50331648ULL
#define BIDX_OFF 100663296ULL
#define TIDX_OFF 101449728ULL
#define IDX_OFF  102236160ULL
// Aliasing plan (all per-row exclusive, read-before-write within the owning wave):
//  - bf16 logits (201.3 MB) occupy exactly the SEL1 region; row r's logits are
//    consumed by row r's wave before it writes sel1 row r.     [proven R4-R7]
//  - per-row summary (128 group-maxima, bf16, 256 B) occupies row r's BIDX
//    (128 B) + TIDX (128 B) slices; consumed in phase 1, overwritten with the
//    real batch/time floats in phase 3 by the same wave.        [new]

__device__ __forceinline__ unsigned ord32(float f) {
    unsigned u = __float_as_uint(f);
    return (u & 0x80000000u) ? ~u : (u | 0x80000000u);
}
__device__ __forceinline__ u16 f2bf(float f) {   // RNE round to bf16
    unsigned u = __float_as_uint(f);
    unsigned r = u + 0x7FFFu + ((u >> 16) & 1u);
    return (u16)(r >> 16);
}
__device__ __forceinline__ float bf2f(short s) {
    return __uint_as_float(((unsigned)(u16)s) << 16);
}
__device__ __forceinline__ u64 pack4bf(float4 v) {
    return (u64)f2bf(v.x) | ((u64)f2bf(v.y) << 16) |
           ((u64)f2bf(v.z) << 32) | ((u64)f2bf(v.w) << 48);
}
__device__ __forceinline__ void lds_fence() {
    asm volatile("s_waitcnt lgkmcnt(0)" ::: "memory");
    __builtin_amdgcn_sched_barrier(0);   // rule #18
}
// descending bitonic sort across 64 lanes (f32)
__device__ __forceinline__ float sort64f_desc(float v, int l) {
#pragma unroll
    for (int k = 2; k <= 64; k <<= 1) {
#pragma unroll
        for (int j = k >> 1; j >= 1; j >>= 1) {
            float o = __shfl_xor(v, j);
            bool takeMax = (((l & j) == 0) == ((l & k) == 0));
            v = takeMax ? fmaxf(v, o) : fminf(v, o);
        }
    }
    return v;
}
// descending bitonic sort across 64 lanes (u64 keys)
__device__ __forceinline__ u64 sort64_desc(u64 v, int l) {
#pragma unroll
    for (int k = 2; k <= 64; k <<= 1) {
#pragma unroll
        for (int j = k >> 1; j >= 1; j >>= 1) {
            u64 o = __shfl_xor(v, j);
            bool takeMax = (((l & j) == 0) == ((l & k) == 0));
            v = takeMax ? (v > o ? v : o) : (v < o ? v : o);
        }
    }
    return v;
}

// ---------------------------------------------------------------------------
// K1: approx logits via bf16 MFMA + per-32n-group maxima summary.
// ---------------------------------------------------------------------------
__global__ __launch_bounds__(256) void k1_logits_bf16(const float* __restrict__ nv1,
                                                      const float* __restrict__ nv2,
                                                      const float* __restrict__ emb,
                                                      float* __restrict__ outBase) {
    u16* logitsB = (u16*)outBase;
    __shared__ u16 Als[128 * 128];   // [m][k] swizzled
    __shared__ u16 Bls[128 * 128];   // [n][k] swizzled (B^T layout)

    const int tid = threadIdx.x;
    const int nt  = blockIdx.x;      // 0..31
    const int bt  = blockIdx.y;      // 0..191
    const int n0  = nt * 128;

#pragma unroll
    for (int it = 0; it < 16; ++it) {
        int f4  = it * 256 + tid;
        int row = f4 >> 5;           // m
        int kq  = f4 & 31;
        float4 a = *(const float4*)(emb + row * 128 + kq * 4);
        int byte = row * 256 + ((kq * 8) ^ ((row & 7) << 4));
        *(u64*)((char*)Als + byte) = pack4bf(a);
    }
#pragma unroll
    for (int it = 0; it < 16; ++it) {
        int f4  = it * 256 + tid;
        int row = f4 >> 5;           // n within tile
        int kq  = f4 & 31;
        const float* src = (kq < 16)
            ? (nv1 + ((size_t)bt * NN + n0 + row) * DD + kq * 4)
            : (nv2 + ((size_t)bt * NN + n0 + row) * DD + (kq - 16) * 4);
        float4 bv = *(const float4*)src;
        int byte = row * 256 + ((kq * 8) ^ ((row & 7) << 4));
        *(u64*)((char*)Bls + byte) = pack4bf(bv);
    }
    __syncthreads();

    const int w  = tid >> 6;
    const int l  = tid & 63;
    const int mb = (w >> 1) * 64;
    const int nb = (w & 1) * 64;
    const int xr = (l & 7) << 4;

    f32x4 acc[4][4];
#pragma unroll
    for (int mi = 0; mi < 4; ++mi)
#pragma unroll
        for (int ni = 0; ni < 4; ++ni) acc[mi][ni] = {0.f, 0.f, 0.f, 0.f};

#pragma unroll
    for (int ks = 0; ks < 4; ++ks) {
        const int kb = (ks * 64 + (l >> 4) * 16) ^ xr;
        short8 a[4], b[4];
#pragma unroll
        for (int mi = 0; mi < 4; ++mi) {
            int row = mb + mi * 16 + (l & 15);
            a[mi] = *(const short8*)((const char*)Als + row * 256 + kb);
        }
#pragma unroll
        for (int ni = 0; ni < 4; ++ni) {
            int row = nb + ni * 16 + (l & 15);
            b[ni] = *(const short8*)((const char*)Bls + row * 256 + kb);
        }
#pragma unroll
        for (int mi = 0; mi < 4; ++mi)
#pragma unroll
            for (int ni = 0; ni < 4; ++ni)
                acc[mi][ni] = __builtin_amdgcn_mfma_f32_16x16x32_bf16(
                    a[mi], b[ni], acc[mi][ni], 0, 0, 0);
    }

    // C-write (bf16 logits). C/D layout: col = lane&15, row = (lane>>4)*4+reg.
    const size_t rbase = (size_t)bt * MM * NN;
#pragma unroll
    for (int mi = 0; mi < 4; ++mi)
#pragma unroll
        for (int ni = 0; ni < 4; ++ni) {
            int n = n0 + nb + ni * 16 + (l & 15);
#pragma unroll
            for (int r = 0; r < 4; ++r) {
                int m = mb + mi * 16 + (l >> 4) * 4 + r;
                logitsB[rbase + (size_t)m * NN + n] = f2bf(acc[mi][ni][r]);
            }
        }

    // Summary: per-32n-group max of ROUNDED values -> bidx/tidx slices.
    // group g (global, 0..127) = nt*4 + (nb>>5) + pair; pair covers ni {0,1}/{2,3}.
    u16* sum_lo = (u16*)((char*)outBase + BIDX_OFF * 4);  // g in [0,64)
    u16* sum_hi = (u16*)((char*)outBase + TIDX_OFF * 4);  // g in [64,128)
#pragma unroll
    for (int mi = 0; mi < 4; ++mi)
#pragma unroll
        for (int pr = 0; pr < 2; ++pr)
#pragma unroll
            for (int r = 0; r < 4; ++r) {
                float v = fmaxf(bf2f((short)f2bf(acc[mi][pr * 2][r])),
                                bf2f((short)f2bf(acc[mi][pr * 2 + 1][r])));
#pragma unroll
                for (int mk = 1; mk < 16; mk <<= 1)
                    v = fmaxf(v, __shfl_xor(v, mk));
                if ((l & 15) == 0) {
                    int m   = mb + mi * 16 + (l >> 4) * 4 + r;
                    int g   = nt * 4 + (nb >> 5) + pr;
                    int rw  = bt * MM + m;
                    u16 hv  = f2bf(v);
                    if (g < 64) sum_lo[rw * 64 + g]        = hv;
                    else        sum_hi[rw * 64 + (g - 64)] = hv;
                }
            }
}

// ---------------------------------------------------------------------------
// K2 (fused, v5): per row (one wave, wave-private, no __syncthreads):
//  1. read 128 group-maxima (256 B) -> T = 44th largest (2x sort64 + kth-of-2)
//     -> load only qualifying 64B groups -> ballot-compact candidates
//  2. per-lane candidate: exact seq-fmaf fp32 dot (bit-stable, proven)
//  3. bitonic sort-64 (+merge if c>64) -> top-32 desc in lanes 0..31;
//     write idx/batch/time (overwrites this row's summary bytes)
//  4. winner rows via shfl; gather; sel1/sel2 write (overwrites logits row)
// Grid XCD-swizzled (bijective 8x768).
// ---------------------------------------------------------------------------
__global__ __launch_bounds__(256) void k2_fused(const u16* logitsB,
                                                const float* __restrict__ nv1,
                                                const float* __restrict__ nv2,
                                                const float* __restrict__ emb,
                                                float* out) {
    const int tid = threadIdx.x;
    const int l   = tid & 63;
    const int w   = tid >> 6;
    const int bid = (int)blockIdx.x;
    const int swz = (bid & 7) * 768 + (bid >> 3);
    const int row = swz * 4 + w;          // 0..24575
    const int bt  = row >> 7;
    const int m   = row & 127;
    const u16* src = logitsB + (size_t)row * NN;

    __shared__ int   cand[4][CAP];
    __shared__ int   glist[4][128];
    __shared__ float embrow[4][128];

    embrow[w][l]      = emb[m * 128 + l];
    embrow[w][l + 64] = emb[m * 128 + 64 + l];

    // ---- 1a. summary read: lane l <-> groups l and 64+l (coalesced 128B x2) --
    const u16* sum_lo = (const u16*)((const char*)out + BIDX_OFF * 4) + row * 64;
    const u16* sum_hi = (const u16*)((const char*)out + TIDX_OFF * 4) + row * 64;
    const float gm0 = bf2f((short)sum_lo[l]);
    const float gm1 = bf2f((short)sum_hi[l]);

    // ---- 1b. T = KTH-th largest of the 128 gmaxes ----
    const float A = sort64f_desc(gm0, l);
    const float B = sort64f_desc(gm1, l);
    const float INF = __builtin_inff();
    float av = __shfl(A, (l >= 1) ? l - 1 : 0);
    if (l < 1) av = INF;
    int jb = KTH - 1 - l;
    float bv = __shfl(B, (jb >= 0 && jb < 64) ? jb : 0);
    if (jb < 0) bv = INF;
    float mm = (l <= KTH) ? fminf(av, bv) : -INF;
#pragma unroll
    for (int mk = 1; mk < 64; mk <<= 1)
        mm = fmaxf(mm, __shfl_xor(mm, mk));
    const float T = mm;   // >= KTH groups (hence elements) >= T

    // ---- 1c. qualifying-group list ----
    u64 m0 = __ballot(gm0 >= T);
    u64 m1 = __ballot(gm1 >= T);
    const u64 below = (1ull << l) - 1ull;
    const int n0q = (int)__popcll(m0);
    if (gm0 >= T) glist[w][__popcll(m0 & below)] = l;
    if (gm1 >= T) glist[w][n0q + (int)__popcll(m1 & below)] = 64 + l;
    const int ng = n0q + (int)__popcll(m1);   // >= KTH
    lds_fence();

    // ---- 1d. load qualifying groups (64B each, 4 lanes/group), compact ----
    int c = 0;
    const int rounds = (ng + 15) >> 4;
    for (int rd = 0; rd < rounds; ++rd) {
        int gi = rd * 16 + (l >> 2);
        bool act = gi < ng;
        int g = act ? glist[w][gi] : 0;
        short8 v8 = {0, 0, 0, 0, 0, 0, 0, 0};
        if (act) v8 = *(const short8*)(src + g * 32 + (l & 3) * 8);
        int nbase = g * 32 + (l & 3) * 8;
#pragma unroll
        for (int e = 0; e < 8; ++e) {
            bool p = act && (bf2f(v8[e]) >= T);
            u64 mask = __ballot(p);
            if (p) {
                int pos = c + (int)__popcll(mask & below);
                if (pos < CAP) cand[w][pos] = nbase + e;
            }
            c += (int)__popcll(mask);
        }
    }
    if (c > CAP) c = CAP;
    lds_fence();  // cand[] visible wave-wide

    // ---- 2. per-lane candidate dot: exact seq-fmaf fp32 (proven order) ----
    u64 kreg[2] = {0ull, 0ull};
    const int nch = (c + 63) >> 6;   // 1 (common) or 2
    for (int s3 = 0; s3 < nch; ++s3) {
        int s = s3 * 64 + l;
        if (s < c) {
            int n = cand[w][s];
            const float4* c1 = (const float4*)(nv1 + ((size_t)bt * NN + n) * DD);
            const float4* c2 = (const float4*)(nv2 + ((size_t)bt * NN + n) * DD);
            float acc = 0.f;
#pragma unroll
            for (int q = 0; q < 16; ++q) {
                float4 x = c1[q];
                acc = fmaf(embrow[w][q * 4 + 0], x.x, acc);
                acc = fmaf(embrow[w][q * 4 + 1], x.y, acc);
                acc = fmaf(embrow[w][q * 4 + 2], x.z, acc);
                acc = fmaf(embrow[w][q * 4 + 3], x.w, acc);
            }
#pragma unroll
            for (int q = 0; q < 16; ++q) {
                float4 x = c2[q];
                acc = fmaf(embrow[w][64 + q * 4 + 0], x.x, acc);
                acc = fmaf(embrow[w][64 + q * 4 + 1], x.y, acc);
                acc = fmaf(embrow[w][64 + q * 4 + 2], x.z, acc);
                acc = fmaf(embrow[w][64 + q * 4 + 3], x.w, acc);
            }
            kreg[s3] = ((u64)ord32(acc) << 32) | (u64)(0xFFFFFFFFu - (unsigned)n);
        }
    }

    // ---- 3. selection: sort desc; lanes 0..31 hold top-32 in order ----
    u64 top = sort64_desc(kreg[0], l);
    if (c > 64) {                         // wave-uniform branch
        u64 Bk = sort64_desc(kreg[1], l);
        u64 rb = __shfl_xor(Bk, 63);      // reverse: lane l <- 63-l
        u64 M = top > rb ? top : rb;      // bitonic, contains top-64 of 128
#pragma unroll
        for (int j = 32; j >= 1; j >>= 1) {
            u64 o = __shfl_xor(M, j);
            M = ((l & j) == 0) ? (M > o ? M : o) : (M < o ? M : o);
        }
        top = M;
    }

    const int b = bt / NT;
    const int t = bt - b * NT;
    const size_t obase = (size_t)row * TOPK;
    const unsigned mynode = 0xFFFFFFFFu - (unsigned)(top & 0xFFFFFFFFull);
    if (l < TOPK) {
        out[IDX_OFF  + obase + l] = (float)mynode;
        out[BIDX_OFF + obase + l] = (float)b;   // overwrites this row's summary
        out[TIDX_OFF + obase + l] = (float)t;
    }

    // ---- 4. winner gather (shfl of sorted keys) + sel1/sel2 write ----
    int myn[8];
#pragma unroll
    for (int it = 0; it < 8; ++it) {
        int p = it * 4 + (l >> 4);
        u64 kk = __shfl(top, p);
        myn[it] = (int)(0xFFFFFFFFu - (unsigned)(kk & 0xFFFFFFFFull)) & (NN - 1);
    }
    const int j4 = (l & 15) * 4;
#pragma unroll
    for (int it = 0; it < 8; ++it) {
        int p = it * 4 + (l >> 4);
        const float4 s1 = *(const float4*)(nv1 + ((size_t)bt * NN + myn[it]) * DD + j4);
        const float4 s2 = *(const float4*)(nv2 + ((size_t)bt * NN + myn[it]) * DD + j4);
        size_t o = (obase + p) * DD + j4;
        *(float4*)(out + SEL1_OFF + o) = s1;
        *(float4*)(out + SEL2_OFF + o) = s2;
    }
}

extern "C" void kernel_launch(void* const* d_in, const int* in_sizes, int n_in,
                              void* d_out, int out_size, void* d_ws, size_t ws_size,
                              hipStream_t stream) {
    const float* nv1 = (const float*)d_in[0];
    const float* nv2 = (const float*)d_in[1];
    const float* emb = (const float*)d_in[2];
    float* out = (float*)d_out;

    dim3 g1(32, BTc);
    k1_logits_bf16<<<g1, 256, 0, stream>>>(nv1, nv2, emb, out);
    k2_fused<<<24576 / 4, 256, 0, stream>>>((const u16*)d_out, nv1, nv2, emb, out);
}